// Round 1
// baseline (1361.071 us; speedup 1.0000x reference)
//
#include <hip/hip_runtime.h>
#include <math.h>

// Problem constants
// B=32, LQ=512, LK=1024, D=128, E=128, H=8, DK=16, NH=512

// ---------------------------------------------------------------------------
// Kernel 1: time embedding + projection.
// row = b*L + l. out[row][e] = sum_j W[e][j] * sin(t*w[j] + b[j])
// ---------------------------------------------------------------------------
__global__ void embed_project(const float* __restrict__ times,
                              const float* __restrict__ w_t,
                              const float* __restrict__ b_t,
                              const float* __restrict__ W,   // [128,128] row-major [out,in]
                              float* __restrict__ outp) {
    const int row = blockIdx.x;
    const int t = threadIdx.x;   // 0..127
    __shared__ float emb[128];
    const float tv = times[row];
    emb[t] = sinf(tv * w_t[t] + b_t[t]);
    __syncthreads();
    const float4* W4 = reinterpret_cast<const float4*>(W + (size_t)t * 128);
    const float4* e4 = reinterpret_cast<const float4*>(emb);
    float acc = 0.f;
#pragma unroll
    for (int j = 0; j < 32; ++j) {
        float4 w = W4[j];
        float4 ev = e4[j];
        acc = fmaf(w.x, ev.x, acc);
        acc = fmaf(w.y, ev.y, acc);
        acc = fmaf(w.z, ev.z, acc);
        acc = fmaf(w.w, ev.w, acc);
    }
    outp[(size_t)row * 128 + t] = acc;
}

// ---------------------------------------------------------------------------
// Kernel 2: fused scores -> exp -> masked num/den -> ratio.
// Block tile: 128 q-rows x 128 d-channels for one (b, h).  K-chunks of 32.
// x[b][q][h*128+d] = num/den
// ---------------------------------------------------------------------------
__global__ __launch_bounds__(256, 2)
void fused_attn(const float* __restrict__ q_s,   // [B,LQ,128] (e = h*16+j)
                const float* __restrict__ k_s,   // [B,LK,128]
                const float* __restrict__ value, // [B,LK,128]
                const int* __restrict__ mask,    // [B,LK,128]
                float* __restrict__ x) {         // [B,LQ,1024]
    const int bid = blockIdx.x;
    const int qt = bid & 3;          // 4 q-tiles of 128
    const int h  = (bid >> 2) & 7;
    const int b  = bid >> 5;
    const int q0 = qt * 128;
    const int t = threadIdx.x;

    __shared__ float q_t[16][128];   // j-major (transposed) -> conflict-free reads
    __shared__ float k_t[16][32];
    __shared__ float e_t[32][128];   // e[kk][m]
    __shared__ float bn_t[32][132];  // mask*value, padded rows
    __shared__ float bd_t[32][132];  // mask

    // Stage q tile once (transposed into LDS).
    {
        const int m = t & 127, jh = t >> 7;
        const float* src = q_s + ((size_t)(b * 512 + q0 + m)) * 128 + h * 16 + jh * 8;
        float4 v0 = *(const float4*)src;
        float4 v1 = *(const float4*)(src + 4);
        const int j = jh * 8;
        q_t[j+0][m]=v0.x; q_t[j+1][m]=v0.y; q_t[j+2][m]=v0.z; q_t[j+3][m]=v0.w;
        q_t[j+4][m]=v1.x; q_t[j+5][m]=v1.y; q_t[j+6][m]=v1.z; q_t[j+7][m]=v1.w;
    }

    float an[8][8] = {};   // numerator accum: 8 m x 8 d
    float ad[8][8] = {};   // denominator accum

    const int mg = t >> 4;          // 0..15: m = mg*8..+7
    const int dg = t & 15;          // d = dg*4..+3 and 64+dg*4..+3
    const int mb = t & 31, kb = t >> 5;   // scores phase: 4m x 4kk
    const int kkv = t >> 3, dblk = t & 7; // value/mask staging

    for (int kc = 0; kc < 32; ++kc) {
        const int k0 = kc * 32;
        __syncthreads();   // previous nd-loop finished reading LDS
        // Stage k chunk (transposed).
        if (t < 128) {
            const int kk = t & 31, jh2 = t >> 5;
            const float* src = k_s + ((size_t)(b * 1024 + k0 + kk)) * 128 + h * 16 + jh2 * 4;
            float4 v = *(const float4*)src;
            const int j = jh2 * 4;
            k_t[j+0][kk]=v.x; k_t[j+1][kk]=v.y; k_t[j+2][kk]=v.z; k_t[j+3][kk]=v.w;
        }
        // Stage value/mask chunk -> bn (mask*value), bd (mask).
        {
            const float* vsrc = value + ((size_t)(b * 1024 + k0 + kkv)) * 128 + dblk * 4;
            const int*   msrc = mask  + ((size_t)(b * 1024 + k0 + kkv)) * 128 + dblk * 4;
#pragma unroll
            for (int i = 0; i < 4; ++i) {
                float4 vv = *(const float4*)(vsrc + i * 32);
                int4   mm = *(const int4*)(msrc + i * 32);
                float4 bn, bd;
                bn.x = mm.x ? vv.x : 0.f;  bd.x = mm.x ? 1.f : 0.f;
                bn.y = mm.y ? vv.y : 0.f;  bd.y = mm.y ? 1.f : 0.f;
                bn.z = mm.z ? vv.z : 0.f;  bd.z = mm.z ? 1.f : 0.f;
                bn.w = mm.w ? vv.w : 0.f;  bd.w = mm.w ? 1.f : 0.f;
                *(float4*)&bn_t[kkv][dblk*4 + i*32] = bn;
                *(float4*)&bd_t[kkv][dblk*4 + i*32] = bd;
            }
        }
        __syncthreads();   // k_t / bn / bd ready
        // Scores + exp for this chunk: each thread does 4 m x 4 kk.
        {
            float sacc[4][4] = {};
#pragma unroll
            for (int j = 0; j < 16; ++j) {
                float4 q4 = *(const float4*)&q_t[j][mb*4];
                float4 k4 = *(const float4*)&k_t[j][kb*4];
                const float qa[4] = {q4.x,q4.y,q4.z,q4.w};
                const float ka[4] = {k4.x,k4.y,k4.z,k4.w};
#pragma unroll
                for (int i2 = 0; i2 < 4; ++i2)
#pragma unroll
                    for (int c = 0; c < 4; ++c)
                        sacc[i2][c] = fmaf(qa[i2], ka[c], sacc[i2][c]);
            }
            // e = exp(s / sqrt(16)); no max-subtraction needed: cancels in num/den.
#pragma unroll
            for (int c = 0; c < 4; ++c) {
                float4 ev;
                ev.x = __expf(sacc[0][c] * 0.25f);
                ev.y = __expf(sacc[1][c] * 0.25f);
                ev.z = __expf(sacc[2][c] * 0.25f);
                ev.w = __expf(sacc[3][c] * 0.25f);
                *(float4*)&e_t[kb*4 + c][mb*4] = ev;
            }
        }
        __syncthreads();   // e_t ready
        // num/den accumulation: 8m x 8d register tile per thread.
#pragma unroll 4
        for (int kk = 0; kk < 32; ++kk) {
            float4 a0 = *(const float4*)&e_t[kk][mg*8];
            float4 a1 = *(const float4*)&e_t[kk][mg*8 + 4];
            float4 n0 = *(const float4*)&bn_t[kk][dg*4];
            float4 n1 = *(const float4*)&bn_t[kk][64 + dg*4];
            float4 d0 = *(const float4*)&bd_t[kk][dg*4];
            float4 d1 = *(const float4*)&bd_t[kk][64 + dg*4];
            const float av[8] = {a0.x,a0.y,a0.z,a0.w,a1.x,a1.y,a1.z,a1.w};
            const float nv[8] = {n0.x,n0.y,n0.z,n0.w,n1.x,n1.y,n1.z,n1.w};
            const float dv[8] = {d0.x,d0.y,d0.z,d0.w,d1.x,d1.y,d1.z,d1.w};
#pragma unroll
            for (int i2 = 0; i2 < 8; ++i2)
#pragma unroll
                for (int c = 0; c < 8; ++c) {
                    an[i2][c] = fmaf(av[i2], nv[c], an[i2][c]);
                    ad[i2][c] = fmaf(av[i2], dv[c], ad[i2][c]);
                }
        }
    }
    // Epilogue: x = num/den, layout [b][q][h*128 + d]
#pragma unroll
    for (int i2 = 0; i2 < 8; ++i2) {
        const int m = mg*8 + i2;
        float* dst = x + ((size_t)(b*512 + q0 + m)) * 1024 + h * 128;
        float4 o0, o1;
        o0.x = __fdividef(an[i2][0], ad[i2][0]);
        o0.y = __fdividef(an[i2][1], ad[i2][1]);
        o0.z = __fdividef(an[i2][2], ad[i2][2]);
        o0.w = __fdividef(an[i2][3], ad[i2][3]);
        o1.x = __fdividef(an[i2][4], ad[i2][4]);
        o1.y = __fdividef(an[i2][5], ad[i2][5]);
        o1.z = __fdividef(an[i2][6], ad[i2][6]);
        o1.w = __fdividef(an[i2][7], ad[i2][7]);
        *(float4*)(dst + dg*4) = o0;
        *(float4*)(dst + 64 + dg*4) = o1;
    }
}

// ---------------------------------------------------------------------------
// Kernel 3: out[16384,512] = x[16384,1024] @ W2[512,1024]^T
// ---------------------------------------------------------------------------
__global__ __launch_bounds__(256, 2)
void out_gemm(const float* __restrict__ x,
              const float* __restrict__ W2,
              float* __restrict__ outp) {
    const int bid = blockIdx.x;
    const int nt = bid & 3;
    const int rt = bid >> 2;
    const int r0 = rt * 128, n0 = nt * 128;
    const int t = threadIdx.x;
    __shared__ float a_t[32][128];   // x chunk, k-major
    __shared__ float b_t[32][132];   // W2 chunk, k-major, padded
    float acc[8][8] = {};
    const int mg = t >> 4, dg = t & 15;
    const int mr = t & 127, kh = t >> 7;

    for (int kc = 0; kc < 32; ++kc) {
        const int k0 = kc * 32;
        __syncthreads();
        {
            const float* src = x + (size_t)(r0 + mr) * 1024 + k0 + kh * 16;
#pragma unroll
            for (int i = 0; i < 4; ++i) {
                float4 v = *(const float4*)(src + i * 4);
                const int j = kh * 16 + i * 4;
                a_t[j+0][mr]=v.x; a_t[j+1][mr]=v.y; a_t[j+2][mr]=v.z; a_t[j+3][mr]=v.w;
            }
            const float* wsrc = W2 + (size_t)(n0 + mr) * 1024 + k0 + kh * 16;
#pragma unroll
            for (int i = 0; i < 4; ++i) {
                float4 v = *(const float4*)(wsrc + i * 4);
                const int j = kh * 16 + i * 4;
                b_t[j+0][mr]=v.x; b_t[j+1][mr]=v.y; b_t[j+2][mr]=v.z; b_t[j+3][mr]=v.w;
            }
        }
        __syncthreads();
#pragma unroll 4
        for (int kk = 0; kk < 32; ++kk) {
            float4 a0 = *(const float4*)&a_t[kk][mg*8];
            float4 a1 = *(const float4*)&a_t[kk][mg*8+4];
            float4 b0 = *(const float4*)&b_t[kk][dg*4];
            float4 b1 = *(const float4*)&b_t[kk][64+dg*4];
            const float av[8] = {a0.x,a0.y,a0.z,a0.w,a1.x,a1.y,a1.z,a1.w};
            const float bv[8] = {b0.x,b0.y,b0.z,b0.w,b1.x,b1.y,b1.z,b1.w};
#pragma unroll
            for (int i2 = 0; i2 < 8; ++i2)
#pragma unroll
                for (int c = 0; c < 8; ++c)
                    acc[i2][c] = fmaf(av[i2], bv[c], acc[i2][c]);
        }
    }
#pragma unroll
    for (int i2 = 0; i2 < 8; ++i2) {
        const int row = r0 + mg*8 + i2;
        float4 o0 = {acc[i2][0],acc[i2][1],acc[i2][2],acc[i2][3]};
        float4 o1 = {acc[i2][4],acc[i2][5],acc[i2][6],acc[i2][7]};
        *(float4*)&outp[(size_t)row*512 + n0 + dg*4] = o0;
        *(float4*)&outp[(size_t)row*512 + n0 + 64 + dg*4] = o1;
    }
}

// ---------------------------------------------------------------------------
extern "C" void kernel_launch(void* const* d_in, const int* in_sizes, int n_in,
                              void* d_out, int out_size, void* d_ws, size_t ws_size,
                              hipStream_t stream) {
    const float* query = (const float*)d_in[0];   // [32,512]
    const float* key   = (const float*)d_in[1];   // [32,1024]
    const float* value = (const float*)d_in[2];   // [32,1024,128]
    const int*   mask  = (const int*)d_in[3];     // [32,1024,128]
    const float* w_t   = (const float*)d_in[4];   // [128]
    const float* b_t   = (const float*)d_in[5];   // [128]
    const float* W0    = (const float*)d_in[6];   // [128,128]
    const float* W1    = (const float*)d_in[7];   // [128,128]
    const float* W2    = (const float*)d_in[8];   // [512,1024]
    float* outp = (float*)d_out;                  // [32,512,512]
    float* ws = (float*)d_ws;

    float* q_s = ws;                               // 32*512*128  = 2,097,152 f
    float* k_s = q_s + (size_t)32*512*128;         // 32*1024*128 = 4,194,304 f
    float* x   = k_s + (size_t)32*1024*128;        // 32*512*1024 = 16,777,216 f
    // total ws use: ~92.3 MB (float)

    embed_project<<<32*512, 128, 0, stream>>>(query, w_t, b_t, W0, q_s);
    embed_project<<<32*1024, 128, 0, stream>>>(key, w_t, b_t, W1, k_s);
    fused_attn<<<1024, 256, 0, stream>>>(q_s, k_s, value, mask, x);
    out_gemm<<<512, 256, 0, stream>>>(x, W2, outp);
}

// Round 3
// 589.431 us; speedup vs baseline: 2.3091x; 2.3091x over previous
//
#include <hip/hip_runtime.h>
#include <math.h>

// B=32, LQ=512, LK=1024, D=128, E=128, H=8, DK=16, NH=512

typedef _Float16 f16;
typedef _Float16 half8 __attribute__((ext_vector_type(8)));
typedef _Float16 half4 __attribute__((ext_vector_type(4)));
typedef float f32x4 __attribute__((ext_vector_type(4)));

#define MFMA_16x16x32_F16(a, b, c) __builtin_amdgcn_mfma_f32_16x16x32_f16((a), (b), (c), 0, 0, 0)

// ---------------------------------------------------------------------------
// Kernel 1: time embedding + projection -> f16.
// ---------------------------------------------------------------------------
__global__ void embed_project_f16(const float* __restrict__ times,
                                  const float* __restrict__ w_t,
                                  const float* __restrict__ b_t,
                                  const float* __restrict__ W,   // [128,128] [out,in]
                                  f16* __restrict__ outp) {
    const int row = blockIdx.x;
    const int t = threadIdx.x;   // 0..127
    __shared__ float emb[128];
    const float tv = times[row];
    emb[t] = sinf(tv * w_t[t] + b_t[t]);
    __syncthreads();
    const float4* W4 = reinterpret_cast<const float4*>(W + (size_t)t * 128);
    const float4* e4 = reinterpret_cast<const float4*>(emb);
    float acc = 0.f;
#pragma unroll
    for (int j = 0; j < 32; ++j) {
        float4 w = W4[j];
        float4 ev = e4[j];
        acc = fmaf(w.x, ev.x, acc);
        acc = fmaf(w.y, ev.y, acc);
        acc = fmaf(w.z, ev.z, acc);
        acc = fmaf(w.w, ev.w, acc);
    }
    outp[(size_t)row * 128 + t] = (f16)acc;
}

// ---------------------------------------------------------------------------
// Kernel 2: bnbdT[b][n][kk] f16, n<128: mask*value (d=n); n>=128: mask (d=n-128)
// Block: one (b, kk-chunk of 64). Transpose via LDS.
// ---------------------------------------------------------------------------
__global__ __launch_bounds__(256)
void make_bnbdT(const float* __restrict__ value, const int* __restrict__ mask,
                f16* __restrict__ bnbdT) {
    const int b = blockIdx.x >> 4;
    const int k0 = (blockIdx.x & 15) * 64;
    const int t = threadIdx.x;
    __shared__ f16 bnT[128][72];
    __shared__ f16 bdT[128][72];
    const int d4 = (t & 31) * 4, kk0 = t >> 5;   // 8 kk rows per pass
#pragma unroll
    for (int pass = 0; pass < 8; ++pass) {
        const int kk = pass * 8 + kk0;
        const size_t off = ((size_t)(b * 1024 + k0 + kk)) * 128 + d4;
        float4 vv = *(const float4*)(value + off);
        int4 mm = *(const int4*)(mask + off);
        bnT[d4 + 0][kk] = (f16)(mm.x ? vv.x : 0.f);  bdT[d4 + 0][kk] = (f16)(mm.x ? 1.f : 0.f);
        bnT[d4 + 1][kk] = (f16)(mm.y ? vv.y : 0.f);  bdT[d4 + 1][kk] = (f16)(mm.y ? 1.f : 0.f);
        bnT[d4 + 2][kk] = (f16)(mm.z ? vv.z : 0.f);  bdT[d4 + 2][kk] = (f16)(mm.z ? 1.f : 0.f);
        bnT[d4 + 3][kk] = (f16)(mm.w ? vv.w : 0.f);  bdT[d4 + 3][kk] = (f16)(mm.w ? 1.f : 0.f);
    }
    __syncthreads();
    const int kkb = t & 7, nr = t >> 3;   // 32 n-rows per pass
#pragma unroll
    for (int pass = 0; pass < 8; ++pass) {
        const int n = pass * 32 + nr;
        half8 v = (n < 128) ? *(const half8*)&bnT[n][kkb * 8]
                            : *(const half8*)&bdT[n - 128][kkb * 8];
        *(half8*)(bnbdT + ((size_t)(b * 256 + n)) * 1024 + k0 + kkb * 8) = v;
    }
}

// ---------------------------------------------------------------------------
// Kernel 3: f32 -> f16 elementwise (for W2)
// ---------------------------------------------------------------------------
__global__ void cvt_f16(const float* __restrict__ in, f16* __restrict__ out) {
    const int i = blockIdx.x * 256 + threadIdx.x;
    float4 v = ((const float4*)in)[i];
    half4 o = { (f16)v.x, (f16)v.y, (f16)v.z, (f16)v.w };
    ((half4*)out)[i] = o;
}

// ---------------------------------------------------------------------------
// Kernel 4: fused scores->exp->num/den via f16 MFMA.
// Block: (b, h, q-tile of 128). 4 waves as 2x2 (M-half r, N/kk-half c).
// Out cols: 256 = 128 num + 128 den; wave c owns d in [c*64, c*64+64) for both.
// ---------------------------------------------------------------------------
__global__ __launch_bounds__(256, 2)
void fused_attn_mfma(const f16* __restrict__ q_s,     // [B,512,128]
                     const f16* __restrict__ k_s,     // [B,1024,128]
                     const f16* __restrict__ bnbdT,   // [B,256,1024]
                     f16* __restrict__ x16) {         // [B,512,1024]
    const int bid = blockIdx.x;
    const int qt = bid & 3, h = (bid >> 2) & 7, b = bid >> 5;
    const int q0 = qt * 128;
    const int t = threadIdx.x, lane = t & 63, wid = t >> 6;
    const int r = wid >> 1, c = wid & 1;
    const int l15 = lane & 15, g = lane >> 4;

    __shared__ f16 k_t[64][40];     // [kk][j], cols 16..39 stay zero (K-pad)
    __shared__ f16 e_t[128][72];    // [q][kk], pitch 72 -> 16B-aligned, bank-balanced
    __shared__ f16 bv_t[256][72];   // [n][kk]

    half8 zero8 = {};
    // zero k_t once (pad cols must be 0 for the zero-padded K=32 MFMA)
    for (int i = t; i < 64 * 40 / 8; i += 256) ((half8*)k_t)[i] = zero8;

    // q A-fragments, loop-invariant, kept in regs. lane: row=l15, k=g*8+i (k>=16 -> 0)
    half8 qa[4];
    {
        const f16* qbase = q_s + ((size_t)(b * 512 + q0 + r * 64)) * 128 + h * 16 + g * 8;
#pragma unroll
        for (int mt = 0; mt < 4; ++mt) {
            half8 v = zero8;
            if (g < 2) v = *(const half8*)(qbase + (size_t)(mt * 16 + l15) * 128);
            qa[mt] = v;
        }
    }

    f32x4 acc[4][8];
    {
        f32x4 z4 = {};
#pragma unroll
        for (int i = 0; i < 4; ++i)
#pragma unroll
            for (int j = 0; j < 8; ++j) acc[i][j] = z4;
    }

    const f16* kbase = k_s + ((size_t)b * 1024) * 128 + h * 16;
    const f16* bvbase = bnbdT + ((size_t)b * 256) * 1024;
    const int kkb = t & 7, nr = t >> 3;

    for (int kc = 0; kc < 16; ++kc) {
        const int k0 = kc * 64;
        __syncthreads();   // previous chunk's LDS reads done
        // stage k chunk: [64 kk][16 j]
        if (t < 128) {
            const int kk = t >> 1, jh = t & 1;
            *(half8*)&k_t[kk][jh * 8] = *(const half8*)(kbase + (size_t)(k0 + kk) * 128 + jh * 8);
        }
        // stage bnbd chunk: [256 n][64 kk]
#pragma unroll
        for (int pass = 0; pass < 8; ++pass) {
            const int n = pass * 32 + nr;
            *(half8*)&bv_t[n][kkb * 8] =
                *(const half8*)(bvbase + (size_t)n * 1024 + k0 + kkb * 8);
        }
        __syncthreads();
        // scores + exp: wave (r,c): q in [r*64, r*64+64), kk in [c*32, c*32+32)
#pragma unroll
        for (int kt = 0; kt < 2; ++kt) {
            half8 kb = *(const half8*)&k_t[c * 32 + kt * 16 + l15][g * 8];
            f32x4 s[4];
#pragma unroll
            for (int mt = 0; mt < 4; ++mt) {
                f32x4 z = {};
                s[mt] = MFMA_16x16x32_F16(qa[mt], kb, z);
            }
#pragma unroll
            for (int mt = 0; mt < 4; ++mt) {
                const int qrow = r * 64 + mt * 16 + g * 4;
                const int kcol = c * 32 + kt * 16 + l15;
#pragma unroll
                for (int rr = 0; rr < 4; ++rr)
                    e_t[qrow + rr][kcol] = (f16)__expf(s[mt][rr] * 0.25f);
            }
        }
        __syncthreads();   // e_t ready for all waves
        // PV: acc[mt][nt<4]=num(d=c*64+nt*16+l15), acc[mt][nt>=4]=den(same d)
#pragma unroll
        for (int ks = 0; ks < 2; ++ks) {
            half8 af[4];
#pragma unroll
            for (int mt = 0; mt < 4; ++mt)
                af[mt] = *(const half8*)&e_t[r * 64 + mt * 16 + l15][ks * 32 + g * 8];
#pragma unroll
            for (int nt = 0; nt < 8; ++nt) {
                const int n = (nt < 4) ? (c * 64 + nt * 16 + l15)
                                       : (128 + c * 64 + (nt - 4) * 16 + l15);
                half8 bf = *(const half8*)&bv_t[n][ks * 32 + g * 8];
#pragma unroll
                for (int mt = 0; mt < 4; ++mt)
                    acc[mt][nt] = MFMA_16x16x32_F16(af[mt], bf, acc[mt][nt]);
            }
        }
    }
    // epilogue: x = num/den -> f16, layout [b][q][h*128+d]
#pragma unroll
    for (int mt = 0; mt < 4; ++mt) {
#pragma unroll
        for (int nt = 0; nt < 4; ++nt) {
#pragma unroll
            for (int rr = 0; rr < 4; ++rr) {
                const int q = q0 + r * 64 + mt * 16 + g * 4 + rr;
                const int d = c * 64 + nt * 16 + l15;
                const float xv = acc[mt][nt][rr] / acc[mt][nt + 4][rr];
                x16[((size_t)(b * 512 + q)) * 1024 + h * 128 + d] = (f16)xv;
            }
        }
    }
}

// ---------------------------------------------------------------------------
// Kernel 5: out[16384,512] = x16[16384,1024] @ W2f16[512,1024]^T, f16 MFMA
// ---------------------------------------------------------------------------
__global__ __launch_bounds__(256, 2)
void out_gemm_f16(const f16* __restrict__ x16, const f16* __restrict__ w2,
                  float* __restrict__ outp) {
    const int bid = blockIdx.x;
    const int m0 = (bid >> 2) * 128, n0 = (bid & 3) * 128;
    const int t = threadIdx.x, lane = t & 63, wid = t >> 6;
    const int r = wid >> 1, c = wid & 1, l15 = lane & 15, g = lane >> 4;
    __shared__ f16 a_t[128][72];
    __shared__ f16 b_t[128][72];
    f32x4 acc[4][4];
    {
        f32x4 z4 = {};
#pragma unroll
        for (int i = 0; i < 4; ++i)
#pragma unroll
            for (int j = 0; j < 4; ++j) acc[i][j] = z4;
    }
    const int kkb = t & 7, nr = t >> 3;
    for (int kc = 0; kc < 16; ++kc) {
        const int k0 = kc * 64;
        __syncthreads();
#pragma unroll
        for (int pass = 0; pass < 4; ++pass) {
            const int row = pass * 32 + nr;
            *(half8*)&a_t[row][kkb * 8] =
                *(const half8*)(x16 + (size_t)(m0 + row) * 1024 + k0 + kkb * 8);
            *(half8*)&b_t[row][kkb * 8] =
                *(const half8*)(w2 + (size_t)(n0 + row) * 1024 + k0 + kkb * 8);
        }
        __syncthreads();
#pragma unroll
        for (int ks = 0; ks < 2; ++ks) {
            half8 af[4], bf[4];
#pragma unroll
            for (int i = 0; i < 4; ++i) {
                af[i] = *(const half8*)&a_t[r * 64 + i * 16 + l15][ks * 32 + g * 8];
                bf[i] = *(const half8*)&b_t[c * 64 + i * 16 + l15][ks * 32 + g * 8];
            }
#pragma unroll
            for (int i = 0; i < 4; ++i)
#pragma unroll
                for (int j = 0; j < 4; ++j)
                    acc[i][j] = MFMA_16x16x32_F16(af[i], bf[j], acc[i][j]);
        }
    }
#pragma unroll
    for (int i = 0; i < 4; ++i)
#pragma unroll
        for (int j = 0; j < 4; ++j)
#pragma unroll
            for (int rr = 0; rr < 4; ++rr) {
                const int m = m0 + r * 64 + i * 16 + g * 4 + rr;
                const int n = n0 + c * 64 + j * 16 + l15;
                outp[(size_t)m * 512 + n] = acc[i][j][rr];
            }
}

// ---------------------------------------------------------------------------
extern "C" void kernel_launch(void* const* d_in, const int* in_sizes, int n_in,
                              void* d_out, int out_size, void* d_ws, size_t ws_size,
                              hipStream_t stream) {
    const float* query = (const float*)d_in[0];
    const float* key   = (const float*)d_in[1];
    const float* value = (const float*)d_in[2];
    const int*   mask  = (const int*)d_in[3];
    const float* w_t   = (const float*)d_in[4];
    const float* b_t   = (const float*)d_in[5];
    const float* W0    = (const float*)d_in[6];
    const float* W1    = (const float*)d_in[7];
    const float* W2    = (const float*)d_in[8];
    float* outp = (float*)d_out;

    f16* wsh = (f16*)d_ws;
    f16* q_s16  = wsh;                          // 32*512*128  = 2,097,152
    f16* k_s16  = q_s16 + (size_t)2097152;      // 32*1024*128 = 4,194,304
    f16* bnbdT  = k_s16 + (size_t)4194304;      // 32*256*1024 = 8,388,608
    f16* x16    = bnbdT + (size_t)8388608;      // 32*512*1024 = 16,777,216
    f16* w2_16  = x16 + (size_t)16777216;       // 512*1024    = 524,288
    // total ~64 MB

    embed_project_f16<<<32 * 512, 128, 0, stream>>>(query, w_t, b_t, W0, q_s16);
    embed_project_f16<<<32 * 1024, 128, 0, stream>>>(key, w_t, b_t, W1, k_s16);
    make_bnbdT<<<512, 256, 0, stream>>>(value, mask, bnbdT);
    cvt_f16<<<512, 256, 0, stream>>>(W2, w2_16);
    fused_attn_mfma<<<1024, 256, 0, stream>>>(q_s16, k_s16, bnbdT, x16);
    out_gemm_f16<<<512, 256, 0, stream>>>(x16, w2_16, outp);
}

// Round 5
// 271.460 us; speedup vs baseline: 5.0139x; 2.1713x over previous
//
#include <hip/hip_runtime.h>
#include <math.h>

// B=32, LQ=512, LK=1024, D=128, E=128, H=8, DK=16, NH=512

typedef _Float16 f16;
typedef _Float16 half8 __attribute__((ext_vector_type(8)));
typedef _Float16 half4 __attribute__((ext_vector_type(4)));
typedef float f32x4 __attribute__((ext_vector_type(4)));

#define MFMA_16x16x32_F16(a, b, c) __builtin_amdgcn_mfma_f32_16x16x32_f16((a), (b), (c), 0, 0, 0)

// ---------------------------------------------------------------------------
// Kernel 1: fused time-embedding + projection via MFMA.
// Block = 128 rows. bid<128: query rows with W0 -> q_out; else key rows, W1.
// out[row][e] = sum_j sin(t_row*w[j]+b[j]) * W[e][j]
// A-operand (sin embeddings) is computed per-lane directly into MFMA fragment
// registers (no LDS tile), split hi/lo f16 for near-f32 accuracy.
// ---------------------------------------------------------------------------
__global__ __launch_bounds__(256, 2)
void embed_project_mfma(const float* __restrict__ times_q,
                        const float* __restrict__ times_k,
                        const float* __restrict__ W0,
                        const float* __restrict__ W1,
                        const float* __restrict__ wt,
                        const float* __restrict__ bt,
                        f16* __restrict__ q_out,
                        f16* __restrict__ k_out) {
    const int bid = blockIdx.x;
    const bool is_q = bid < 128;
    const float* times = is_q ? times_q : times_k;
    const float* W = is_q ? W0 : W1;
    f16* outp = is_q ? q_out : k_out;
    const int r0 = (is_q ? bid : bid - 128) * 128;

    __shared__ f16 w_lds[128][136];  // [e][j], pitch 136 (17x8): 2-way bank alias = free
    __shared__ float wv[128];
    __shared__ float bvv[128];
    __shared__ float tv_s[128];

    const int t = threadIdx.x;
    if (t < 128) { wv[t] = wt[t]; bvv[t] = bt[t]; tv_s[t] = times[r0 + t]; }
    // stage W (f32 -> f16 hi): full 128x128, 16 float4 per thread
#pragma unroll
    for (int p = 0; p < 16; ++p) {
        const int idx = p * 256 + t;
        const int row = idx >> 5, c4 = idx & 31;
        float4 v = *(const float4*)(W + (size_t)row * 128 + c4 * 4);
        half4 o = { (f16)v.x, (f16)v.y, (f16)v.z, (f16)v.w };
        *(half4*)&w_lds[row][c4 * 4] = o;
    }
    __syncthreads();

    const int lane = t & 63, wid = t >> 6;
    const int r = wid >> 1, c = wid & 1, l15 = lane & 15, g = lane >> 4;
    f32x4 acc[4][4];
    {
        f32x4 z4 = {};
#pragma unroll
        for (int i = 0; i < 4; ++i)
#pragma unroll
            for (int j = 0; j < 4; ++j) acc[i][j] = z4;
    }
#pragma unroll
    for (int ks = 0; ks < 4; ++ks) {
        half8 bf[4];
#pragma unroll
        for (int nt = 0; nt < 4; ++nt)
            bf[nt] = *(const half8*)&w_lds[c * 64 + nt * 16 + l15][ks * 32 + g * 8];
#pragma unroll
        for (int mt = 0; mt < 4; ++mt) {
            const float tvv = tv_s[r * 64 + mt * 16 + l15];
            half8 ahi, alo;
#pragma unroll
            for (int i = 0; i < 8; ++i) {
                const int j = ks * 32 + g * 8 + i;
                const float s = sinf(tvv * wv[j] + bvv[j]);
                const f16 hi = (f16)s;
                ahi[i] = hi;
                alo[i] = (f16)(s - (float)hi);
            }
#pragma unroll
            for (int nt = 0; nt < 4; ++nt) {
                acc[mt][nt] = MFMA_16x16x32_F16(ahi, bf[nt], acc[mt][nt]);
                acc[mt][nt] = MFMA_16x16x32_F16(alo, bf[nt], acc[mt][nt]);
            }
        }
    }
#pragma unroll
    for (int i = 0; i < 4; ++i)
#pragma unroll
        for (int j = 0; j < 4; ++j)
#pragma unroll
            for (int rr = 0; rr < 4; ++rr) {
                const int row = r0 + r * 64 + i * 16 + g * 4 + rr;
                const int e = c * 64 + j * 16 + l15;
                outp[(size_t)row * 128 + e] = (f16)acc[i][j][rr];
            }
}

// ---------------------------------------------------------------------------
// Kernel 2: bnbdT[b][n][kk] f16, n<128: mask*value (d=n); n>=128: mask (d=n-128)
// ---------------------------------------------------------------------------
__global__ __launch_bounds__(256)
void make_bnbdT(const float* __restrict__ value, const int* __restrict__ mask,
                f16* __restrict__ bnbdT) {
    const int b = blockIdx.x >> 4;
    const int k0 = (blockIdx.x & 15) * 64;
    const int t = threadIdx.x;
    __shared__ f16 bnT[128][72];
    __shared__ f16 bdT[128][72];
    const int d4 = (t & 31) * 4, kk0 = t >> 5;
#pragma unroll
    for (int pass = 0; pass < 8; ++pass) {
        const int kk = pass * 8 + kk0;
        const size_t off = ((size_t)(b * 1024 + k0 + kk)) * 128 + d4;
        float4 vv = *(const float4*)(value + off);
        int4 mm = *(const int4*)(mask + off);
        bnT[d4 + 0][kk] = (f16)(mm.x ? vv.x : 0.f);  bdT[d4 + 0][kk] = (f16)(mm.x ? 1.f : 0.f);
        bnT[d4 + 1][kk] = (f16)(mm.y ? vv.y : 0.f);  bdT[d4 + 1][kk] = (f16)(mm.y ? 1.f : 0.f);
        bnT[d4 + 2][kk] = (f16)(mm.z ? vv.z : 0.f);  bdT[d4 + 2][kk] = (f16)(mm.z ? 1.f : 0.f);
        bnT[d4 + 3][kk] = (f16)(mm.w ? vv.w : 0.f);  bdT[d4 + 3][kk] = (f16)(mm.w ? 1.f : 0.f);
    }
    __syncthreads();
    const int kkb = t & 7, nr = t >> 3;
#pragma unroll
    for (int pass = 0; pass < 8; ++pass) {
        const int n = pass * 32 + nr;
        half8 v = (n < 128) ? *(const half8*)&bnT[n][kkb * 8]
                            : *(const half8*)&bdT[n - 128][kkb * 8];
        *(half8*)(bnbdT + ((size_t)(b * 256 + n)) * 1024 + k0 + kkb * 8) = v;
    }
}

// ---------------------------------------------------------------------------
// Kernel 3: f32 -> f16 elementwise (for W2)
// ---------------------------------------------------------------------------
__global__ void cvt_f16(const float* __restrict__ in, f16* __restrict__ out) {
    const int i = blockIdx.x * 256 + threadIdx.x;
    float4 v = ((const float4*)in)[i];
    half4 o = { (f16)v.x, (f16)v.y, (f16)v.z, (f16)v.w };
    ((half4*)out)[i] = o;
}

// ---------------------------------------------------------------------------
// Kernel 4: fused scores->exp->num/den via f16 MFMA.
// ---------------------------------------------------------------------------
__global__ __launch_bounds__(256, 2)
void fused_attn_mfma(const f16* __restrict__ q_s,     // [B,512,128]
                     const f16* __restrict__ k_s,     // [B,1024,128]
                     const f16* __restrict__ bnbdT,   // [B,256,1024]
                     f16* __restrict__ x16) {         // [B,512,1024]
    const int bid = blockIdx.x;
    const int qt = bid & 3, h = (bid >> 2) & 7, b = bid >> 5;
    const int q0 = qt * 128;
    const int t = threadIdx.x, lane = t & 63, wid = t >> 6;
    const int r = wid >> 1, c = wid & 1;
    const int l15 = lane & 15, g = lane >> 4;

    __shared__ f16 k_t[64][40];     // [kk][j], cols 16..39 stay zero
    __shared__ f16 e_t[128][72];    // [q][kk]
    __shared__ f16 bv_t[256][72];   // [n][kk]

    half8 zero8 = {};
    for (int i = t; i < 64 * 40 / 8; i += 256) ((half8*)k_t)[i] = zero8;

    half8 qa[4];
    {
        const f16* qbase = q_s + ((size_t)(b * 512 + q0 + r * 64)) * 128 + h * 16 + g * 8;
#pragma unroll
        for (int mt = 0; mt < 4; ++mt) {
            half8 v = zero8;
            if (g < 2) v = *(const half8*)(qbase + (size_t)(mt * 16 + l15) * 128);
            qa[mt] = v;
        }
    }

    f32x4 acc[4][8];
    {
        f32x4 z4 = {};
#pragma unroll
        for (int i = 0; i < 4; ++i)
#pragma unroll
            for (int j = 0; j < 8; ++j) acc[i][j] = z4;
    }

    const f16* kbase = k_s + ((size_t)b * 1024) * 128 + h * 16;
    const f16* bvbase = bnbdT + ((size_t)b * 256) * 1024;
    const int kkb = t & 7, nr = t >> 3;

    for (int kc = 0; kc < 16; ++kc) {
        const int k0 = kc * 64;
        __syncthreads();
        if (t < 128) {
            const int kk = t >> 1, jh = t & 1;
            *(half8*)&k_t[kk][jh * 8] = *(const half8*)(kbase + (size_t)(k0 + kk) * 128 + jh * 8);
        }
#pragma unroll
        for (int pass = 0; pass < 8; ++pass) {
            const int n = pass * 32 + nr;
            *(half8*)&bv_t[n][kkb * 8] =
                *(const half8*)(bvbase + (size_t)n * 1024 + k0 + kkb * 8);
        }
        __syncthreads();
#pragma unroll
        for (int kt = 0; kt < 2; ++kt) {
            half8 kb = *(const half8*)&k_t[c * 32 + kt * 16 + l15][g * 8];
            f32x4 s[4];
#pragma unroll
            for (int mt = 0; mt < 4; ++mt) {
                f32x4 z = {};
                s[mt] = MFMA_16x16x32_F16(qa[mt], kb, z);
            }
#pragma unroll
            for (int mt = 0; mt < 4; ++mt) {
                const int qrow = r * 64 + mt * 16 + g * 4;
                const int kcol = c * 32 + kt * 16 + l15;
#pragma unroll
                for (int rr = 0; rr < 4; ++rr)
                    e_t[qrow + rr][kcol] = (f16)__expf(s[mt][rr] * 0.25f);
            }
        }
        __syncthreads();
#pragma unroll
        for (int ks = 0; ks < 2; ++ks) {
            half8 af[4];
#pragma unroll
            for (int mt = 0; mt < 4; ++mt)
                af[mt] = *(const half8*)&e_t[r * 64 + mt * 16 + l15][ks * 32 + g * 8];
#pragma unroll
            for (int nt = 0; nt < 8; ++nt) {
                const int n = (nt < 4) ? (c * 64 + nt * 16 + l15)
                                       : (128 + c * 64 + (nt - 4) * 16 + l15);
                half8 bf = *(const half8*)&bv_t[n][ks * 32 + g * 8];
#pragma unroll
                for (int mt = 0; mt < 4; ++mt)
                    acc[mt][nt] = MFMA_16x16x32_F16(af[mt], bf, acc[mt][nt]);
            }
        }
    }
#pragma unroll
    for (int mt = 0; mt < 4; ++mt) {
#pragma unroll
        for (int nt = 0; nt < 4; ++nt) {
#pragma unroll
            for (int rr = 0; rr < 4; ++rr) {
                const int q = q0 + r * 64 + mt * 16 + g * 4 + rr;
                const int d = c * 64 + nt * 16 + l15;
                const float xv = acc[mt][nt][rr] / acc[mt][nt + 4][rr];
                x16[((size_t)(b * 512 + q)) * 1024 + h * 128 + d] = (f16)xv;
            }
        }
    }
}

// ---------------------------------------------------------------------------
// Kernel 5: out[16384,512] = x16[16384,1024] @ W2f16[512,1024]^T, f16 MFMA
// ---------------------------------------------------------------------------
__global__ __launch_bounds__(256, 2)
void out_gemm_f16(const f16* __restrict__ x16, const f16* __restrict__ w2,
                  float* __restrict__ outp) {
    const int bid = blockIdx.x;
    const int m0 = (bid >> 2) * 128, n0 = (bid & 3) * 128;
    const int t = threadIdx.x, lane = t & 63, wid = t >> 6;
    const int r = wid >> 1, c = wid & 1, l15 = lane & 15, g = lane >> 4;
    __shared__ f16 a_t[128][72];
    __shared__ f16 b_t[128][72];
    f32x4 acc[4][4];
    {
        f32x4 z4 = {};
#pragma unroll
        for (int i = 0; i < 4; ++i)
#pragma unroll
            for (int j = 0; j < 4; ++j) acc[i][j] = z4;
    }
    const int kkb = t & 7, nr = t >> 3;
    for (int kc = 0; kc < 16; ++kc) {
        const int k0 = kc * 64;
        __syncthreads();
#pragma unroll
        for (int pass = 0; pass < 4; ++pass) {
            const int row = pass * 32 + nr;
            *(half8*)&a_t[row][kkb * 8] =
                *(const half8*)(x16 + (size_t)(m0 + row) * 1024 + k0 + kkb * 8);
            *(half8*)&b_t[row][kkb * 8] =
                *(const half8*)(w2 + (size_t)(n0 + row) * 1024 + k0 + kkb * 8);
        }
        __syncthreads();
#pragma unroll
        for (int ks = 0; ks < 2; ++ks) {
            half8 af[4], bf[4];
#pragma unroll
            for (int i = 0; i < 4; ++i) {
                af[i] = *(const half8*)&a_t[r * 64 + i * 16 + l15][ks * 32 + g * 8];
                bf[i] = *(const half8*)&b_t[c * 64 + i * 16 + l15][ks * 32 + g * 8];
            }
#pragma unroll
            for (int i = 0; i < 4; ++i)
#pragma unroll
                for (int j = 0; j < 4; ++j)
                    acc[i][j] = MFMA_16x16x32_F16(af[i], bf[j], acc[i][j]);
        }
    }
#pragma unroll
    for (int i = 0; i < 4; ++i)
#pragma unroll
        for (int j = 0; j < 4; ++j)
#pragma unroll
            for (int rr = 0; rr < 4; ++rr) {
                const int m = m0 + r * 64 + i * 16 + g * 4 + rr;
                const int n = n0 + c * 64 + j * 16 + l15;
                outp[(size_t)m * 512 + n] = acc[i][j][rr];
            }
}

// ---------------------------------------------------------------------------
extern "C" void kernel_launch(void* const* d_in, const int* in_sizes, int n_in,
                              void* d_out, int out_size, void* d_ws, size_t ws_size,
                              hipStream_t stream) {
    const float* query = (const float*)d_in[0];
    const float* key   = (const float*)d_in[1];
    const float* value = (const float*)d_in[2];
    const int*   mask  = (const int*)d_in[3];
    const float* w_t   = (const float*)d_in[4];
    const float* b_t   = (const float*)d_in[5];
    const float* W0    = (const float*)d_in[6];
    const float* W1    = (const float*)d_in[7];
    const float* W2    = (const float*)d_in[8];
    float* outp = (float*)d_out;

    f16* wsh = (f16*)d_ws;
    f16* q_s16  = wsh;                          // 32*512*128  = 2,097,152
    f16* k_s16  = q_s16 + (size_t)2097152;      // 32*1024*128 = 4,194,304
    f16* bnbdT  = k_s16 + (size_t)4194304;      // 32*256*1024 = 8,388,608
    f16* x16    = bnbdT + (size_t)8388608;      // 32*512*1024 = 16,777,216
    f16* w2_16  = x16 + (size_t)16777216;       // 512*1024    = 524,288

    embed_project_mfma<<<384, 256, 0, stream>>>(query, key, W0, W1, w_t, b_t,
                                                q_s16, k_s16);
    make_bnbdT<<<512, 256, 0, stream>>>(value, mask, bnbdT);
    cvt_f16<<<512, 256, 0, stream>>>(W2, w2_16);
    fused_attn_mfma<<<1024, 256, 0, stream>>>(q_s16, k_s16, bnbdT, x16);
    out_gemm_f16<<<512, 256, 0, stream>>>(x16, w2_16, outp);
}

// Round 8
// 263.867 us; speedup vs baseline: 5.1582x; 1.0288x over previous
//
#include <hip/hip_runtime.h>
#include <math.h>

// B=32, LQ=512, LK=1024, D=128, E=128, H=8, DK=16, NH=512

typedef _Float16 f16;
typedef _Float16 half8 __attribute__((ext_vector_type(8)));
typedef _Float16 half4 __attribute__((ext_vector_type(4)));
typedef float f32x4 __attribute__((ext_vector_type(4)));

#define MFMA_16x16x32_F16(a, b, c) __builtin_amdgcn_mfma_f32_16x16x32_f16((a), (b), (c), 0, 0, 0)

// ---------------------------------------------------------------------------
// Kernel 1: fused time-embedding + projection via MFMA (hi/lo f16 split).
// ---------------------------------------------------------------------------
__global__ __launch_bounds__(256, 2)
void embed_project_mfma(const float* __restrict__ times_q,
                        const float* __restrict__ times_k,
                        const float* __restrict__ W0,
                        const float* __restrict__ W1,
                        const float* __restrict__ wt,
                        const float* __restrict__ bt,
                        f16* __restrict__ q_out,
                        f16* __restrict__ k_out) {
    const int bid = blockIdx.x;
    const bool is_q = bid < 128;
    const float* times = is_q ? times_q : times_k;
    const float* W = is_q ? W0 : W1;
    f16* outp = is_q ? q_out : k_out;
    const int r0 = (is_q ? bid : bid - 128) * 128;

    __shared__ f16 w_lds[128][136];  // [e][j], pitch 136: 2-way bank alias = free
    __shared__ float wv[128];
    __shared__ float bvv[128];
    __shared__ float tv_s[128];

    const int t = threadIdx.x;
    if (t < 128) { wv[t] = wt[t]; bvv[t] = bt[t]; tv_s[t] = times[r0 + t]; }
#pragma unroll
    for (int p = 0; p < 16; ++p) {
        const int idx = p * 256 + t;
        const int row = idx >> 5, c4 = idx & 31;
        float4 v = *(const float4*)(W + (size_t)row * 128 + c4 * 4);
        half4 o = { (f16)v.x, (f16)v.y, (f16)v.z, (f16)v.w };
        *(half4*)&w_lds[row][c4 * 4] = o;
    }
    __syncthreads();

    const int lane = t & 63, wid = t >> 6;
    const int r = wid >> 1, c = wid & 1, l15 = lane & 15, g = lane >> 4;
    f32x4 acc[4][4];
    {
        f32x4 z4 = {};
#pragma unroll
        for (int i = 0; i < 4; ++i)
#pragma unroll
            for (int j = 0; j < 4; ++j) acc[i][j] = z4;
    }
#pragma unroll
    for (int ks = 0; ks < 4; ++ks) {
        half8 bf[4];
#pragma unroll
        for (int nt = 0; nt < 4; ++nt)
            bf[nt] = *(const half8*)&w_lds[c * 64 + nt * 16 + l15][ks * 32 + g * 8];
#pragma unroll
        for (int mt = 0; mt < 4; ++mt) {
            const float tvv = tv_s[r * 64 + mt * 16 + l15];
            half8 ahi, alo;
#pragma unroll
            for (int i = 0; i < 8; ++i) {
                const int j = ks * 32 + g * 8 + i;
                const float s = sinf(tvv * wv[j] + bvv[j]);
                const f16 hi = (f16)s;
                ahi[i] = hi;
                alo[i] = (f16)(s - (float)hi);
            }
#pragma unroll
            for (int nt = 0; nt < 4; ++nt) {
                acc[mt][nt] = MFMA_16x16x32_F16(ahi, bf[nt], acc[mt][nt]);
                acc[mt][nt] = MFMA_16x16x32_F16(alo, bf[nt], acc[mt][nt]);
            }
        }
    }
#pragma unroll
    for (int i = 0; i < 4; ++i)
#pragma unroll
        for (int j = 0; j < 4; ++j)
#pragma unroll
            for (int rr = 0; rr < 4; ++rr) {
                const int row = r0 + r * 64 + i * 16 + g * 4 + rr;
                const int e = c * 64 + j * 16 + l15;
                outp[(size_t)row * 128 + e] = (f16)acc[i][j][rr];
            }
}

// ---------------------------------------------------------------------------
// Kernel 2: bnbdT[b][n][kk] f16, n<128: mask*value (d=n); n>=128: mask (d=n-128)
// ---------------------------------------------------------------------------
__global__ __launch_bounds__(256)
void make_bnbdT(const float* __restrict__ value, const int* __restrict__ mask,
                f16* __restrict__ bnbdT) {
    const int b = blockIdx.x >> 4;
    const int k0 = (blockIdx.x & 15) * 64;
    const int t = threadIdx.x;
    __shared__ f16 bnT[128][72];
    __shared__ f16 bdT[128][72];
    const int d4 = (t & 31) * 4, kk0 = t >> 5;
#pragma unroll
    for (int pass = 0; pass < 8; ++pass) {
        const int kk = pass * 8 + kk0;
        const size_t off = ((size_t)(b * 1024 + k0 + kk)) * 128 + d4;
        float4 vv = *(const float4*)(value + off);
        int4 mm = *(const int4*)(mask + off);
        bnT[d4 + 0][kk] = (f16)(mm.x ? vv.x : 0.f);  bdT[d4 + 0][kk] = (f16)(mm.x ? 1.f : 0.f);
        bnT[d4 + 1][kk] = (f16)(mm.y ? vv.y : 0.f);  bdT[d4 + 1][kk] = (f16)(mm.y ? 1.f : 0.f);
        bnT[d4 + 2][kk] = (f16)(mm.z ? vv.z : 0.f);  bdT[d4 + 2][kk] = (f16)(mm.z ? 1.f : 0.f);
        bnT[d4 + 3][kk] = (f16)(mm.w ? vv.w : 0.f);  bdT[d4 + 3][kk] = (f16)(mm.w ? 1.f : 0.f);
    }
    __syncthreads();
    const int kkb = t & 7, nr = t >> 3;
#pragma unroll
    for (int pass = 0; pass < 8; ++pass) {
        const int n = pass * 32 + nr;
        half8 v = (n < 128) ? *(const half8*)&bnT[n][kkb * 8]
                            : *(const half8*)&bdT[n - 128][kkb * 8];
        *(half8*)(bnbdT + ((size_t)(b * 256 + n)) * 1024 + k0 + kkb * 8) = v;
    }
}

// ---------------------------------------------------------------------------
// Kernel 3: f32 -> f16 elementwise (for W2)
// ---------------------------------------------------------------------------
__global__ void cvt_f16(const float* __restrict__ in, f16* __restrict__ out) {
    const int i = blockIdx.x * 256 + threadIdx.x;
    float4 v = ((const float4*)in)[i];
    half4 o = { (f16)v.x, (f16)v.y, (f16)v.z, (f16)v.w };
    ((half4*)out)[i] = o;
}

// ---------------------------------------------------------------------------
// Kernel 4: fused scores->exp->num/den via f16 MFMA.
// Scores use SWAPPED operands MFMA(k, q): C col=lane&15 -> q, row -> kk.
// Each lane then owns 4 consecutive kk of one q row -> packed ds_write_b64
// (replaces 32 conflicted scalar f16 writes per thread per iter).
// ---------------------------------------------------------------------------
__global__ __launch_bounds__(256, 2)
void fused_attn_mfma(const f16* __restrict__ q_s,     // [B,512,128]
                     const f16* __restrict__ k_s,     // [B,1024,128]
                     const f16* __restrict__ bnbdT,   // [B,256,1024]
                     f16* __restrict__ x16) {         // [B,512,1024]
    const int bid = blockIdx.x;
    const int qt = bid & 3, h = (bid >> 2) & 7, b = bid >> 5;
    const int q0 = qt * 128;
    const int t = threadIdx.x, lane = t & 63, wid = t >> 6;
    const int r = wid >> 1, c = wid & 1;
    const int l15 = lane & 15, g = lane >> 4;

    __shared__ f16 k_t[64][40];     // [kk][j], cols 16..39 stay zero
    __shared__ f16 e_t[128][72];    // [q][kk]
    __shared__ f16 bv_t[256][72];   // [n][kk]

    half8 zero8 = {};
    for (int i = t; i < 64 * 40 / 8; i += 256) ((half8*)k_t)[i] = zero8;

    half8 qa[4];
    {
        const f16* qbase = q_s + ((size_t)(b * 512 + q0 + r * 64)) * 128 + h * 16 + g * 8;
#pragma unroll
        for (int mt = 0; mt < 4; ++mt) {
            half8 v = zero8;
            if (g < 2) v = *(const half8*)(qbase + (size_t)(mt * 16 + l15) * 128);
            qa[mt] = v;
        }
    }

    f32x4 acc[4][8];
    {
        f32x4 z4 = {};
#pragma unroll
        for (int i = 0; i < 4; ++i)
#pragma unroll
            for (int j = 0; j < 8; ++j) acc[i][j] = z4;
    }

    const f16* kbase = k_s + ((size_t)b * 1024) * 128 + h * 16;
    const f16* bvbase = bnbdT + ((size_t)b * 256) * 1024;
    const int kkb = t & 7, nr = t >> 3;

    for (int kc = 0; kc < 16; ++kc) {
        const int k0 = kc * 64;
        __syncthreads();
        if (t < 128) {
            const int kk = t >> 1, jh = t & 1;
            *(half8*)&k_t[kk][jh * 8] = *(const half8*)(kbase + (size_t)(k0 + kk) * 128 + jh * 8);
        }
#pragma unroll
        for (int pass = 0; pass < 8; ++pass) {
            const int n = pass * 32 + nr;
            *(half8*)&bv_t[n][kkb * 8] =
                *(const half8*)(bvbase + (size_t)n * 1024 + k0 + kkb * 8);
        }
        __syncthreads();
        // scores (swapped): s = MFMA(k_frag, q_frag) -> C[kk][q]
        // lane: q = r*64 + mt*16 + l15, kk = c*32 + kt*16 + g*4 + rr
#pragma unroll
        for (int kt = 0; kt < 2; ++kt) {
            half8 kb = *(const half8*)&k_t[c * 32 + kt * 16 + l15][g * 8];
            f32x4 s[4];
#pragma unroll
            for (int mt = 0; mt < 4; ++mt) {
                f32x4 z = {};
                s[mt] = MFMA_16x16x32_F16(kb, qa[mt], z);
            }
#pragma unroll
            for (int mt = 0; mt < 4; ++mt) {
                half4 ev;
#pragma unroll
                for (int rr = 0; rr < 4; ++rr)
                    ev[rr] = (f16)__expf(s[mt][rr] * 0.25f);
                *(half4*)&e_t[r * 64 + mt * 16 + l15][c * 32 + kt * 16 + g * 4] = ev;
            }
        }
        __syncthreads();
#pragma unroll
        for (int ks = 0; ks < 2; ++ks) {
            half8 af[4];
#pragma unroll
            for (int mt = 0; mt < 4; ++mt)
                af[mt] = *(const half8*)&e_t[r * 64 + mt * 16 + l15][ks * 32 + g * 8];
#pragma unroll
            for (int nt = 0; nt < 8; ++nt) {
                const int n = (nt < 4) ? (c * 64 + nt * 16 + l15)
                                       : (128 + c * 64 + (nt - 4) * 16 + l15);
                half8 bf = *(const half8*)&bv_t[n][ks * 32 + g * 8];
#pragma unroll
                for (int mt = 0; mt < 4; ++mt)
                    acc[mt][nt] = MFMA_16x16x32_F16(af[mt], bf, acc[mt][nt]);
            }
        }
    }
#pragma unroll
    for (int mt = 0; mt < 4; ++mt) {
#pragma unroll
        for (int nt = 0; nt < 4; ++nt) {
#pragma unroll
            for (int rr = 0; rr < 4; ++rr) {
                const int q = q0 + r * 64 + mt * 16 + g * 4 + rr;
                const int d = c * 64 + nt * 16 + l15;
                const float xv = acc[mt][nt][rr] / acc[mt][nt + 4][rr];
                x16[((size_t)(b * 512 + q)) * 1024 + h * 128 + d] = (f16)xv;
            }
        }
    }
}

// ---------------------------------------------------------------------------
// Kernel 5: out[16384,512] = x16[16384,1024] @ W2f16[512,1024]^T, f16 MFMA
// ---------------------------------------------------------------------------
__global__ __launch_bounds__(256, 2)
void out_gemm_f16(const f16* __restrict__ x16, const f16* __restrict__ w2,
                  float* __restrict__ outp) {
    const int bid = blockIdx.x;
    const int m0 = (bid >> 2) * 128, n0 = (bid & 3) * 128;
    const int t = threadIdx.x, lane = t & 63, wid = t >> 6;
    const int r = wid >> 1, c = wid & 1, l15 = lane & 15, g = lane >> 4;
    __shared__ f16 a_t[128][72];
    __shared__ f16 b_t[128][72];
    f32x4 acc[4][4];
    {
        f32x4 z4 = {};
#pragma unroll
        for (int i = 0; i < 4; ++i)
#pragma unroll
            for (int j = 0; j < 4; ++j) acc[i][j] = z4;
    }
    const int kkb = t & 7, nr = t >> 3;
    for (int kc = 0; kc < 16; ++kc) {
        const int k0 = kc * 64;
        __syncthreads();
#pragma unroll
        for (int pass = 0; pass < 4; ++pass) {
            const int row = pass * 32 + nr;
            *(half8*)&a_t[row][kkb * 8] =
                *(const half8*)(x16 + (size_t)(m0 + row) * 1024 + k0 + kkb * 8);
            *(half8*)&b_t[row][kkb * 8] =
                *(const half8*)(w2 + (size_t)(n0 + row) * 1024 + k0 + kkb * 8);
        }
        __syncthreads();
#pragma unroll
        for (int ks = 0; ks < 2; ++ks) {
            half8 af[4], bf[4];
#pragma unroll
            for (int i = 0; i < 4; ++i) {
                af[i] = *(const half8*)&a_t[r * 64 + i * 16 + l15][ks * 32 + g * 8];
                bf[i] = *(const half8*)&b_t[c * 64 + i * 16 + l15][ks * 32 + g * 8];
            }
#pragma unroll
            for (int i = 0; i < 4; ++i)
#pragma unroll
                for (int j = 0; j < 4; ++j)
                    acc[i][j] = MFMA_16x16x32_F16(af[i], bf[j], acc[i][j]);
        }
    }
#pragma unroll
    for (int i = 0; i < 4; ++i)
#pragma unroll
        for (int j = 0; j < 4; ++j)
#pragma unroll
            for (int rr = 0; rr < 4; ++rr) {
                const int m = m0 + r * 64 + i * 16 + g * 4 + rr;
                const int n = n0 + c * 64 + j * 16 + l15;
                outp[(size_t)m * 512 + n] = acc[i][j][rr];
            }
}

// ---------------------------------------------------------------------------
extern "C" void kernel_launch(void* const* d_in, const int* in_sizes, int n_in,
                              void* d_out, int out_size, void* d_ws, size_t ws_size,
                              hipStream_t stream) {
    const float* query = (const float*)d_in[0];
    const float* key   = (const float*)d_in[1];
    const float* value = (const float*)d_in[2];
    const int*   mask  = (const int*)d_in[3];
    const float* w_t   = (const float*)d_in[4];
    const float* b_t   = (const float*)d_in[5];
    const float* W0    = (const float*)d_in[6];
    const float* W1    = (const float*)d_in[7];
    const float* W2    = (const float*)d_in[8];
    float* outp = (float*)d_out;

    f16* wsh = (f16*)d_ws;
    f16* q_s16  = wsh;                          // 32*512*128  = 2,097,152
    f16* k_s16  = q_s16 + (size_t)2097152;      // 32*1024*128 = 4,194,304
    f16* bnbdT  = k_s16 + (size_t)4194304;      // 32*256*1024 = 8,388,608
    f16* x16    = bnbdT + (size_t)8388608;      // 32*512*1024 = 16,777,216
    f16* w2_16  = x16 + (size_t)16777216;       // 512*1024    = 524,288

    embed_project_mfma<<<384, 256, 0, stream>>>(query, key, W0, W1, w_t, b_t,
                                                q_s16, k_s16);
    make_bnbdT<<<512, 256, 0, stream>>>(value, mask, bnbdT);
    cvt_f16<<<512, 256, 0, stream>>>(W2, w2_16);
    fused_attn_mfma<<<1024, 256, 0, stream>>>(q_s16, k_s16, bnbdT, x16);
    out_gemm_f16<<<512, 256, 0, stream>>>(x16, w2_16, outp);
}

// Round 9
// 234.597 us; speedup vs baseline: 5.8017x; 1.1248x over previous
//
#include <hip/hip_runtime.h>
#include <math.h>

// B=32, LQ=512, LK=1024, D=128, E=128, H=8, DK=16, NH=512

typedef _Float16 f16;
typedef _Float16 half8 __attribute__((ext_vector_type(8)));
typedef _Float16 half4 __attribute__((ext_vector_type(4)));
typedef float f32x4 __attribute__((ext_vector_type(4)));

#define MFMA_16x16x32_F16(a, b, c) __builtin_amdgcn_mfma_f32_16x16x32_f16((a), (b), (c), 0, 0, 0)

// ---------------------------------------------------------------------------
// Kernel 1: fused time-embedding + projection via MFMA (hi/lo f16 split).
// ---------------------------------------------------------------------------
__global__ __launch_bounds__(256, 2)
void embed_project_mfma(const float* __restrict__ times_q,
                        const float* __restrict__ times_k,
                        const float* __restrict__ W0,
                        const float* __restrict__ W1,
                        const float* __restrict__ wt,
                        const float* __restrict__ bt,
                        f16* __restrict__ q_out,
                        f16* __restrict__ k_out) {
    const int bid = blockIdx.x;
    const bool is_q = bid < 128;
    const float* times = is_q ? times_q : times_k;
    const float* W = is_q ? W0 : W1;
    f16* outp = is_q ? q_out : k_out;
    const int r0 = (is_q ? bid : bid - 128) * 128;

    __shared__ f16 w_lds[128][136];  // [e][j], pitch 136: 2-way bank alias = free
    __shared__ float wv[128];
    __shared__ float bvv[128];
    __shared__ float tv_s[128];

    const int t = threadIdx.x;
    if (t < 128) { wv[t] = wt[t]; bvv[t] = bt[t]; tv_s[t] = times[r0 + t]; }
#pragma unroll
    for (int p = 0; p < 16; ++p) {
        const int idx = p * 256 + t;
        const int row = idx >> 5, c4 = idx & 31;
        float4 v = *(const float4*)(W + (size_t)row * 128 + c4 * 4);
        half4 o = { (f16)v.x, (f16)v.y, (f16)v.z, (f16)v.w };
        *(half4*)&w_lds[row][c4 * 4] = o;
    }
    __syncthreads();

    const int lane = t & 63, wid = t >> 6;
    const int r = wid >> 1, c = wid & 1, l15 = lane & 15, g = lane >> 4;
    f32x4 acc[4][4];
    {
        f32x4 z4 = {};
#pragma unroll
        for (int i = 0; i < 4; ++i)
#pragma unroll
            for (int j = 0; j < 4; ++j) acc[i][j] = z4;
    }
#pragma unroll
    for (int ks = 0; ks < 4; ++ks) {
        half8 bf[4];
#pragma unroll
        for (int nt = 0; nt < 4; ++nt)
            bf[nt] = *(const half8*)&w_lds[c * 64 + nt * 16 + l15][ks * 32 + g * 8];
#pragma unroll
        for (int mt = 0; mt < 4; ++mt) {
            const float tvv = tv_s[r * 64 + mt * 16 + l15];
            half8 ahi, alo;
#pragma unroll
            for (int i = 0; i < 8; ++i) {
                const int j = ks * 32 + g * 8 + i;
                const float s = sinf(tvv * wv[j] + bvv[j]);
                const f16 hi = (f16)s;
                ahi[i] = hi;
                alo[i] = (f16)(s - (float)hi);
            }
#pragma unroll
            for (int nt = 0; nt < 4; ++nt) {
                acc[mt][nt] = MFMA_16x16x32_F16(ahi, bf[nt], acc[mt][nt]);
                acc[mt][nt] = MFMA_16x16x32_F16(alo, bf[nt], acc[mt][nt]);
            }
        }
    }
#pragma unroll
    for (int i = 0; i < 4; ++i)
#pragma unroll
        for (int j = 0; j < 4; ++j)
#pragma unroll
            for (int rr = 0; rr < 4; ++rr) {
                const int row = r0 + r * 64 + i * 16 + g * 4 + rr;
                const int e = c * 64 + j * 16 + l15;
                outp[(size_t)row * 128 + e] = (f16)acc[i][j][rr];
            }
}

// ---------------------------------------------------------------------------
// Kernel 2: bnbdT[b][n][kk] f16, n<128: mask*value (d=n); n>=128: mask (d=n-128)
// ---------------------------------------------------------------------------
__global__ __launch_bounds__(256)
void make_bnbdT(const float* __restrict__ value, const int* __restrict__ mask,
                f16* __restrict__ bnbdT) {
    const int b = blockIdx.x >> 4;
    const int k0 = (blockIdx.x & 15) * 64;
    const int t = threadIdx.x;
    __shared__ f16 bnT[128][72];
    __shared__ f16 bdT[128][72];
    const int d4 = (t & 31) * 4, kk0 = t >> 5;
#pragma unroll
    for (int pass = 0; pass < 8; ++pass) {
        const int kk = pass * 8 + kk0;
        const size_t off = ((size_t)(b * 1024 + k0 + kk)) * 128 + d4;
        float4 vv = *(const float4*)(value + off);
        int4 mm = *(const int4*)(mask + off);
        bnT[d4 + 0][kk] = (f16)(mm.x ? vv.x : 0.f);  bdT[d4 + 0][kk] = (f16)(mm.x ? 1.f : 0.f);
        bnT[d4 + 1][kk] = (f16)(mm.y ? vv.y : 0.f);  bdT[d4 + 1][kk] = (f16)(mm.y ? 1.f : 0.f);
        bnT[d4 + 2][kk] = (f16)(mm.z ? vv.z : 0.f);  bdT[d4 + 2][kk] = (f16)(mm.z ? 1.f : 0.f);
        bnT[d4 + 3][kk] = (f16)(mm.w ? vv.w : 0.f);  bdT[d4 + 3][kk] = (f16)(mm.w ? 1.f : 0.f);
    }
    __syncthreads();
    const int kkb = t & 7, nr = t >> 3;
#pragma unroll
    for (int pass = 0; pass < 8; ++pass) {
        const int n = pass * 32 + nr;
        half8 v = (n < 128) ? *(const half8*)&bnT[n][kkb * 8]
                            : *(const half8*)&bdT[n - 128][kkb * 8];
        *(half8*)(bnbdT + ((size_t)(b * 256 + n)) * 1024 + k0 + kkb * 8) = v;
    }
}

// ---------------------------------------------------------------------------
// Kernel 3: f32 -> f16 elementwise (for W2)
// ---------------------------------------------------------------------------
__global__ void cvt_f16(const float* __restrict__ in, f16* __restrict__ out) {
    const int i = blockIdx.x * 256 + threadIdx.x;
    float4 v = ((const float4*)in)[i];
    half4 o = { (f16)v.x, (f16)v.y, (f16)v.z, (f16)v.w };
    ((half4*)out)[i] = o;
}

// ---------------------------------------------------------------------------
// Kernel 4: fused scores->exp->num/den via f16 MFMA.
// Round 9: (a) async-STAGE: next chunk's global loads issued right after
// barrier B so HBM latency hides under scores+PV; (b) XCD swizzle: all 32
// blocks of one batch b land on one XCD (p%8==b%8) for L2 residency.
// ---------------------------------------------------------------------------
__global__ __launch_bounds__(256, 2)
void fused_attn_mfma(const f16* __restrict__ q_s,     // [B,512,128]
                     const f16* __restrict__ k_s,     // [B,1024,128]
                     const f16* __restrict__ bnbdT,   // [B,256,1024]
                     f16* __restrict__ x16) {         // [B,512,1024]
    // XCD-aware logical block id: p = (b>>3)*256 + hq*8 + (b&7)
    const int p = blockIdx.x;
    const int b = (p & 7) + ((p >> 8) << 3);
    const int hq = (p >> 3) & 31;
    const int h = hq >> 2, qt = hq & 3;
    const int q0 = qt * 128;
    const int t = threadIdx.x, lane = t & 63, wid = t >> 6;
    const int r = wid >> 1, c = wid & 1;
    const int l15 = lane & 15, g = lane >> 4;

    __shared__ f16 k_t[64][40];     // [kk][j], cols 16..39 stay zero
    __shared__ f16 e_t[128][72];    // [q][kk]
    __shared__ f16 bv_t[256][72];   // [n][kk]

    half8 zero8 = {};
    for (int i = t; i < 64 * 40 / 8; i += 256) ((half8*)k_t)[i] = zero8;

    half8 qa[4];
    {
        const f16* qbase = q_s + ((size_t)(b * 512 + q0 + r * 64)) * 128 + h * 16 + g * 8;
#pragma unroll
        for (int mt = 0; mt < 4; ++mt) {
            half8 v = zero8;
            if (g < 2) v = *(const half8*)(qbase + (size_t)(mt * 16 + l15) * 128);
            qa[mt] = v;
        }
    }

    f32x4 acc[4][8];
    {
        f32x4 z4 = {};
#pragma unroll
        for (int i = 0; i < 4; ++i)
#pragma unroll
            for (int j = 0; j < 8; ++j) acc[i][j] = z4;
    }

    const f16* kbase = k_s + ((size_t)b * 1024) * 128 + h * 16;
    const f16* bvbase = bnbdT + ((size_t)b * 256) * 1024;
    const int kkb = t & 7, nr = t >> 3;

    // staging registers (async-STAGE)
    half8 bv_reg[8];
    half8 k_reg;

#define FA_LOAD_CHUNK(K0)                                                          \
    do {                                                                           \
        if (t < 128)                                                               \
            k_reg = *(const half8*)(kbase + (size_t)((K0) + (t >> 1)) * 128 +      \
                                    (t & 1) * 8);                                  \
        _Pragma("unroll")                                                          \
        for (int pass = 0; pass < 8; ++pass)                                       \
            bv_reg[pass] = *(const half8*)(bvbase + (size_t)(pass * 32 + nr) *     \
                                           1024 + (K0) + kkb * 8);                 \
    } while (0)

    FA_LOAD_CHUNK(0);

    for (int kc = 0; kc < 16; ++kc) {
        __syncthreads();   // A: previous PV done reading k_t/bv_t
        if (t < 128)
            *(half8*)&k_t[t >> 1][(t & 1) * 8] = k_reg;
#pragma unroll
        for (int pass = 0; pass < 8; ++pass)
            *(half8*)&bv_t[pass * 32 + nr][kkb * 8] = bv_reg[pass];
        __syncthreads();   // B: tiles ready
        if (kc < 15) FA_LOAD_CHUNK((kc + 1) * 64);   // latency hides under scores+PV

        // scores (swapped): s = MFMA(k_frag, q_frag) -> C[kk][q]
        // lane: q = r*64 + mt*16 + l15, kk = c*32 + kt*16 + g*4 + rr
#pragma unroll
        for (int kt = 0; kt < 2; ++kt) {
            half8 kb = *(const half8*)&k_t[c * 32 + kt * 16 + l15][g * 8];
            f32x4 s[4];
#pragma unroll
            for (int mt = 0; mt < 4; ++mt) {
                f32x4 z = {};
                s[mt] = MFMA_16x16x32_F16(kb, qa[mt], z);
            }
#pragma unroll
            for (int mt = 0; mt < 4; ++mt) {
                half4 ev;
#pragma unroll
                for (int rr = 0; rr < 4; ++rr)
                    ev[rr] = (f16)__expf(s[mt][rr] * 0.25f);
                *(half4*)&e_t[r * 64 + mt * 16 + l15][c * 32 + kt * 16 + g * 4] = ev;
            }
        }
        __syncthreads();   // C: e_t ready
#pragma unroll
        for (int ks = 0; ks < 2; ++ks) {
            half8 af[4];
#pragma unroll
            for (int mt = 0; mt < 4; ++mt)
                af[mt] = *(const half8*)&e_t[r * 64 + mt * 16 + l15][ks * 32 + g * 8];
#pragma unroll
            for (int nt = 0; nt < 8; ++nt) {
                const int n = (nt < 4) ? (c * 64 + nt * 16 + l15)
                                       : (128 + c * 64 + (nt - 4) * 16 + l15);
                half8 bf = *(const half8*)&bv_t[n][ks * 32 + g * 8];
#pragma unroll
                for (int mt = 0; mt < 4; ++mt)
                    acc[mt][nt] = MFMA_16x16x32_F16(af[mt], bf, acc[mt][nt]);
            }
        }
    }
#undef FA_LOAD_CHUNK

#pragma unroll
    for (int mt = 0; mt < 4; ++mt) {
#pragma unroll
        for (int nt = 0; nt < 4; ++nt) {
#pragma unroll
            for (int rr = 0; rr < 4; ++rr) {
                const int q = q0 + r * 64 + mt * 16 + g * 4 + rr;
                const int d = c * 64 + nt * 16 + l15;
                const float xv = acc[mt][nt][rr] / acc[mt][nt + 4][rr];
                x16[((size_t)(b * 512 + q)) * 1024 + h * 128 + d] = (f16)xv;
            }
        }
    }
}

// ---------------------------------------------------------------------------
// Kernel 5: out[16384,512] = x16[16384,1024] @ W2f16[512,1024]^T, f16 MFMA
// Depth-2 register prefetch (compute phase too short to hide HBM at depth 1).
// ---------------------------------------------------------------------------
__global__ __launch_bounds__(256, 2)
void out_gemm_f16(const f16* __restrict__ x16, const f16* __restrict__ w2,
                  float* __restrict__ outp) {
    const int bid = blockIdx.x;
    const int m0 = (bid >> 2) * 128, n0 = (bid & 3) * 128;
    const int t = threadIdx.x, lane = t & 63, wid = t >> 6;
    const int r = wid >> 1, c = wid & 1, l15 = lane & 15, g = lane >> 4;
    __shared__ f16 a_t[128][72];
    __shared__ f16 b_t[128][72];
    f32x4 acc[4][4];
    {
        f32x4 z4 = {};
#pragma unroll
        for (int i = 0; i < 4; ++i)
#pragma unroll
            for (int j = 0; j < 4; ++j) acc[i][j] = z4;
    }
    const int kkb = t & 7, nr = t >> 3;

    half8 a_reg[2][4], b_reg[2][4];
#define OG_LOAD(BUF, K0)                                                           \
    do {                                                                           \
        _Pragma("unroll")                                                          \
        for (int pass = 0; pass < 4; ++pass) {                                     \
            const int row = pass * 32 + nr;                                        \
            a_reg[BUF][pass] = *(const half8*)(x16 + (size_t)(m0 + row) * 1024 +   \
                                               (K0) + kkb * 8);                    \
            b_reg[BUF][pass] = *(const half8*)(w2 + (size_t)(n0 + row) * 1024 +    \
                                               (K0) + kkb * 8);                    \
        }                                                                          \
    } while (0)

    OG_LOAD(0, 0);
    OG_LOAD(1, 64);

    for (int kc = 0; kc < 16; ++kc) {
        const int cur = kc & 1;
        __syncthreads();
#pragma unroll
        for (int pass = 0; pass < 4; ++pass) {
            const int row = pass * 32 + nr;
            *(half8*)&a_t[row][kkb * 8] = a_reg[cur][pass];
            *(half8*)&b_t[row][kkb * 8] = b_reg[cur][pass];
        }
        __syncthreads();
        if (kc + 2 < 16) OG_LOAD(cur, (kc + 2) * 64);
#pragma unroll
        for (int ks = 0; ks < 2; ++ks) {
            half8 af[4], bf[4];
#pragma unroll
            for (int i = 0; i < 4; ++i) {
                af[i] = *(const half8*)&a_t[r * 64 + i * 16 + l15][ks * 32 + g * 8];
                bf[i] = *(const half8*)&b_t[c * 64 + i * 16 + l15][ks * 32 + g * 8];
            }
#pragma unroll
            for (int i = 0; i < 4; ++i)
#pragma unroll
                for (int j = 0; j < 4; ++j)
                    acc[i][j] = MFMA_16x16x32_F16(af[i], bf[j], acc[i][j]);
        }
    }
#undef OG_LOAD

#pragma unroll
    for (int i = 0; i < 4; ++i)
#pragma unroll
        for (int j = 0; j < 4; ++j)
#pragma unroll
            for (int rr = 0; rr < 4; ++rr) {
                const int m = m0 + r * 64 + i * 16 + g * 4 + rr;
                const int n = n0 + c * 64 + j * 16 + l15;
                outp[(size_t)m * 512 + n] = acc[i][j][rr];
            }
}

// ---------------------------------------------------------------------------
extern "C" void kernel_launch(void* const* d_in, const int* in_sizes, int n_in,
                              void* d_out, int out_size, void* d_ws, size_t ws_size,
                              hipStream_t stream) {
    const float* query = (const float*)d_in[0];
    const float* key   = (const float*)d_in[1];
    const float* value = (const float*)d_in[2];
    const int*   mask  = (const int*)d_in[3];
    const float* w_t   = (const float*)d_in[4];
    const float* b_t   = (const float*)d_in[5];
    const float* W0    = (const float*)d_in[6];
    const float* W1    = (const float*)d_in[7];
    const float* W2    = (const float*)d_in[8];
    float* outp = (float*)d_out;

    f16* wsh = (f16*)d_ws;
    f16* q_s16  = wsh;                          // 32*512*128  = 2,097,152
    f16* k_s16  = q_s16 + (size_t)2097152;      // 32*1024*128 = 4,194,304
    f16* bnbdT  = k_s16 + (size_t)4194304;      // 32*256*1024 = 8,388,608
    f16* x16    = bnbdT + (size_t)8388608;      // 32*512*1024 = 16,777,216
    f16* w2_16  = x16 + (size_t)16777216;       // 512*1024    = 524,288

    embed_project_mfma<<<384, 256, 0, stream>>>(query, key, W0, W1, w_t, b_t,
                                                q_s16, k_s16);
    make_bnbdT<<<512, 256, 0, stream>>>(value, mask, bnbdT);
    cvt_f16<<<512, 256, 0, stream>>>(W2, w2_16);
    fused_attn_mfma<<<1024, 256, 0, stream>>>(q_s16, k_s16, bnbdT, x16);
    out_gemm_f16<<<512, 256, 0, stream>>>(x16, w2_16, outp);
}